// Round 1
// baseline (902.001 us; speedup 1.0000x reference)
//
#include <hip/hip_runtime.h>
#include <hip/hip_bf16.h>

// Problem constants
#define B_SZ   4096
#define OBS_N  128
#define L_N    4
#define D_N    8
#define BINS_N 16
#define S_N    32          // L*D
#define HID    512
#define CHUNK  32768       // q-MLP rows per chunk (B*S/4)

typedef __bf16 bf16x8_t __attribute__((ext_vector_type(8)));
typedef float  f32x4_t  __attribute__((ext_vector_type(4)));

__device__ inline float fast_tanh(float x) {
    float xc = fminf(fmaxf(x, -15.f), 15.f);
    float e  = __expf(2.f * xc);
    return (e - 1.f) * __builtin_amdgcn_rcpf(e + 1.f);
}

__device__ inline void gld_lds16(const void* g, void* l) {
    __builtin_amdgcn_global_load_lds(
        (const __attribute__((address_space(1))) void*)g,
        (__attribute__((address_space(3))) void*)l, 16, 0, 0);
}

// ---------------- prep kernels ----------------

// dst (N, Kd) bf16 = transpose of src (Ksrc, N) fp32 rows [k0src, k0src+Kcopy), zero-pad k>=Kcopy
__global__ __launch_bounds__(256) void transpose_cast(
    const float* __restrict__ src, __hip_bfloat16* __restrict__ dst,
    int N, int Kcopy, int Kd, int k0src)
{
    int idx = blockIdx.x * 256 + threadIdx.x;
    if (idx >= N * Kd) return;
    int n = idx / Kd, k = idx % Kd;
    float v = (k < Kcopy) ? src[(size_t)(k0src + k) * N + n] : 0.f;
    dst[idx] = __float2bfloat16(v);
}

__global__ __launch_bounds__(256) void cast_kernel(
    const float* __restrict__ src, __hip_bfloat16* __restrict__ dst, int n)
{
    int i = blockIdx.x * 256 + threadIdx.x;
    if (i < n) dst[i] = __float2bfloat16(src[i]);
}

__global__ __launch_bounds__(256) void zero_kernel(float* __restrict__ p, int n)
{
    int i = blockIdx.x * 256 + threadIdx.x;
    if (i < n) p[i] = 0.f;
}

// ---------------- GEMM (m97-style) ----------------
// C(M,512) = A(M,K) @ Bt(512,K)^T ; EPI=0: store fp32 raw; EPI=1: bf16(tanh(acc+bias))
template <int EPI>
__global__ __launch_bounds__(256) void gemm_bt(
    const __hip_bfloat16* __restrict__ A,
    const __hip_bfloat16* __restrict__ Bt,
    const float* __restrict__ bias,
    void* __restrict__ Cout,
    int K)
{
    __shared__ __hip_bfloat16 As[128 * 32];
    __shared__ __hip_bfloat16 Bs[128 * 32];
    const int tid  = threadIdx.x;
    const int wave = tid >> 6, lane = tid & 63;
    const int quad = lane >> 4, t = lane & 15;
    const int wr = wave >> 1, wc = wave & 1;
    const long m0 = (long)blockIdx.x * 128;
    const int  n0 = blockIdx.y * 128;

    f32x4_t acc[4][4] = {};

    const int lrow  = lane >> 2;       // 0..15
    const int lkoff = (lane & 3) * 8;  // element offset within 32-wide K chunk

    const __hip_bfloat16* Ag0 = A  + (m0 + wave * 32 +      lrow) * (long)K + lkoff;
    const __hip_bfloat16* Ag1 = A  + (m0 + wave * 32 + 16 + lrow) * (long)K + lkoff;
    const __hip_bfloat16* Bg0 = Bt + (long)(n0 + wave * 32 +      lrow) * K + lkoff;
    const __hip_bfloat16* Bg1 = Bt + (long)(n0 + wave * 32 + 16 + lrow) * K + lkoff;
    __hip_bfloat16* AsB0 = &As[(wave * 32) * 32];
    __hip_bfloat16* AsB1 = &As[(wave * 32 + 16) * 32];
    __hip_bfloat16* BsB0 = &Bs[(wave * 32) * 32];
    __hip_bfloat16* BsB1 = &Bs[(wave * 32 + 16) * 32];

    for (int k0 = 0; k0 < K; k0 += 32) {
        gld_lds16(Ag0 + k0, AsB0);
        gld_lds16(Ag1 + k0, AsB1);
        gld_lds16(Bg0 + k0, BsB0);
        gld_lds16(Bg1 + k0, BsB1);
        __syncthreads();
        bf16x8_t af[4], bfr[4];
        #pragma unroll
        for (int i = 0; i < 4; ++i)
            af[i] = *(const bf16x8_t*)&As[(wr * 64 + i * 16 + t) * 32 + quad * 8];
        #pragma unroll
        for (int j = 0; j < 4; ++j)
            bfr[j] = *(const bf16x8_t*)&Bs[(wc * 64 + j * 16 + t) * 32 + quad * 8];
        #pragma unroll
        for (int i = 0; i < 4; ++i)
            #pragma unroll
            for (int j = 0; j < 4; ++j)
                acc[i][j] = __builtin_amdgcn_mfma_f32_16x16x32_bf16(af[i], bfr[j], acc[i][j], 0, 0, 0);
        __syncthreads();
    }

    #pragma unroll
    for (int i = 0; i < 4; ++i) {
        const long rbase = m0 + wr * 64 + i * 16 + quad * 4;
        #pragma unroll
        for (int j = 0; j < 4; ++j) {
            const int col = n0 + wc * 64 + j * 16 + t;
            #pragma unroll
            for (int r = 0; r < 4; ++r) {
                float v = acc[i][j][r];
                if constexpr (EPI == 1) {
                    v = fast_tanh(v + bias[col]);
                    ((__hip_bfloat16*)Cout)[(rbase + r) * 512 + col] = __float2bfloat16(v);
                } else {
                    ((float*)Cout)[(rbase + r) * 512 + col] = v;
                }
            }
        }
    }
}

// ---------------- q layer 0: h0 = tanh(p[b] + actions(b,s)@W0b + b0) ----------------
__global__ __launch_bounds__(512) void h0_kernel(
    const float* __restrict__ p,         // (4096,512) fp32 = obs @ W0[:128]
    const int* __restrict__ category,    // (4096,4,8)
    const float* __restrict__ qw0,       // (136,512) fp32 (rows 128..135 = action part)
    const float* __restrict__ qb0,       // (512)
    __hip_bfloat16* __restrict__ h0,     // (CHUNK,512)
    int r0)
{
    int lr = blockIdx.x;
    int n  = threadIdx.x;
    int r  = r0 + lr;
    int b  = r >> 5, s = r & 31;
    __shared__ float act[8];
    if (n < 8) {
        int d = n;
        int U = (s >> 3) + ((d < (s & 7)) ? 1 : 0);
        float a = 0.f;
        if (U > 0) {
            float w = 0.125f, cum = 0.f;
            for (int j = 0; j < U; ++j) {
                cum += (float)category[b * 32 + j * 8 + d] * w;
                if (j == U - 1) a = -1.f + cum + 0.5f * w;
                w *= 0.0625f;
            }
        }
        act[d] = a;
    }
    __syncthreads();
    float v = p[(size_t)b * 512 + n] + qb0[n];
    #pragma unroll
    for (int d = 0; d < 8; ++d)
        v = fmaf(act[d], qw0[(128 + d) * 512 + n], v);
    h0[(size_t)lr * 512 + n] = __float2bfloat16(fast_tanh(v));
}

// ---------------- q layer 3 (diagonal only) ----------------
__device__ inline float blo(unsigned u) { return __uint_as_float(u << 16); }
__device__ inline float bhi(unsigned u) { return __uint_as_float(u & 0xffff0000u); }
__device__ inline float dot8(uint4 a, uint4 b, float acc) {
    acc = fmaf(blo(a.x), blo(b.x), acc); acc = fmaf(bhi(a.x), bhi(b.x), acc);
    acc = fmaf(blo(a.y), blo(b.y), acc); acc = fmaf(bhi(a.y), bhi(b.y), acc);
    acc = fmaf(blo(a.z), blo(b.z), acc); acc = fmaf(bhi(a.z), bhi(b.z), acc);
    acc = fmaf(blo(a.w), blo(b.w), acc); acc = fmaf(bhi(a.w), bhi(b.w), acc);
    return acc;
}

__global__ __launch_bounds__(256) void adv_kernel(
    const __hip_bfloat16* __restrict__ h2,   // (CHUNK,512)
    const __hip_bfloat16* __restrict__ w3t,  // (512,512): [out][k]
    const float* __restrict__ qb3,
    float* __restrict__ advout,              // d_out + 4096
    int r0)
{
    int tid = blockIdx.x * 256 + threadIdx.x;
    int lr = tid >> 4, c = tid & 15;
    int r = r0 + lr, b = r >> 5, s = r & 31;
    int o = s * 16 + c;
    const uint4* h = (const uint4*)(h2 + (size_t)lr * 512);
    const uint4* w = (const uint4*)(w3t + (size_t)o * 512);
    float acc = 0.f;
    #pragma unroll 8
    for (int i = 0; i < 64; ++i)
        acc = dot8(h[i], w[i], acc);
    advout[(size_t)b * 512 + o] = acc + qb3[o];
}

// ---------------- v final layer ----------------
__global__ __launch_bounds__(256) void value_kernel(
    const __hip_bfloat16* __restrict__ hv2,  // (4096,512)
    const float* __restrict__ vw3,           // (512,1)
    const float* __restrict__ vb3,
    float* __restrict__ out)
{
    int b = blockIdx.x * 256 + threadIdx.x;
    if (b >= 4096) return;
    const uint4* h = (const uint4*)(hv2 + (size_t)b * 512);
    float acc = 0.f;
    for (int i = 0; i < 64; ++i) {
        uint4 hu = h[i];
        const float* w = vw3 + i * 8;
        acc = fmaf(blo(hu.x), w[0], acc); acc = fmaf(bhi(hu.x), w[1], acc);
        acc = fmaf(blo(hu.y), w[2], acc); acc = fmaf(bhi(hu.y), w[3], acc);
        acc = fmaf(blo(hu.z), w[4], acc); acc = fmaf(bhi(hu.z), w[5], acc);
        acc = fmaf(blo(hu.w), w[6], acc); acc = fmaf(bhi(hu.w), w[7], acc);
    }
    out[b] = acc + vb3[0];
}

// ---------------- launch ----------------
extern "C" void kernel_launch(void* const* d_in, const int* in_sizes, int n_in,
                              void* d_out, int out_size, void* d_ws, size_t ws_size,
                              hipStream_t stream) {
    const float* obs      = (const float*)d_in[0];
    const int*   category = (const int*)d_in[1];
    const float* v_w0 = (const float*)d_in[2];
    const float* v_b0 = (const float*)d_in[3];
    const float* v_w1 = (const float*)d_in[4];
    const float* v_b1 = (const float*)d_in[5];
    const float* v_w2 = (const float*)d_in[6];
    const float* v_b2 = (const float*)d_in[7];
    const float* v_w3 = (const float*)d_in[8];
    const float* v_b3 = (const float*)d_in[9];
    const float* q_w0 = (const float*)d_in[10];
    const float* q_b0 = (const float*)d_in[11];
    const float* q_w1 = (const float*)d_in[12];
    const float* q_b1 = (const float*)d_in[13];
    const float* q_w2 = (const float*)d_in[14];
    const float* q_b2 = (const float*)d_in[15];
    const float* q_w3 = (const float*)d_in[16];
    const float* q_b3 = (const float*)d_in[17];

    char* ws = (char*)d_ws;
    __hip_bfloat16* obs_bf = (__hip_bfloat16*)(ws + 0);              // 1 MB
    __hip_bfloat16* w0t    = (__hip_bfloat16*)(ws + 1048576);        // (512,128)
    __hip_bfloat16* w1t    = (__hip_bfloat16*)(ws + 1179648);        // (512,512)
    __hip_bfloat16* w2t    = (__hip_bfloat16*)(ws + 1703936);
    __hip_bfloat16* w3t    = (__hip_bfloat16*)(ws + 2228224);
    __hip_bfloat16* vw0t   = (__hip_bfloat16*)(ws + 2752512);        // (512,128)
    __hip_bfloat16* vw1t   = (__hip_bfloat16*)(ws + 2883584);
    __hip_bfloat16* vw2t   = (__hip_bfloat16*)(ws + 3407872);
    float*          p      = (float*)         (ws + 3932160);        // (4096,512) fp32
    __hip_bfloat16* hva    = (__hip_bfloat16*)(ws + 12320768);       // (4096,512)
    __hip_bfloat16* hvb    = (__hip_bfloat16*)(ws + 16515072);
    __hip_bfloat16* ha     = (__hip_bfloat16*)(ws + 20709376);       // (CHUNK,512)
    __hip_bfloat16* hb     = (__hip_bfloat16*)(ws + 54263808);       // ends 87.8 MB

    float* out       = (float*)d_out;
    float* out_value = out;
    float* out_adv   = out + 4096;
    float* out_nbias = out + 4096 + (size_t)B_SZ * 512;

    // --- prep: casts + weight transposes ---
    cast_kernel<<<2048, 256, 0, stream>>>(obs, obs_bf, B_SZ * OBS_N);
    transpose_cast<<<256,  256, 0, stream>>>(q_w0, w0t,  512, 128, 128, 0);
    transpose_cast<<<1024, 256, 0, stream>>>(q_w1, w1t,  512, 512, 512, 0);
    transpose_cast<<<1024, 256, 0, stream>>>(q_w2, w2t,  512, 512, 512, 0);
    transpose_cast<<<1024, 256, 0, stream>>>(q_w3, w3t,  512, 512, 512, 0);
    transpose_cast<<<256,  256, 0, stream>>>(v_w0, vw0t, 512, 128, 128, 0);
    transpose_cast<<<1024, 256, 0, stream>>>(v_w1, vw1t, 512, 512, 512, 0);
    transpose_cast<<<1024, 256, 0, stream>>>(v_w2, vw2t, 512, 512, 512, 0);

    // --- p = obs @ W0[:128] (fp32 out, no activation) ---
    gemm_bt<0><<<dim3(32, 4), 256, 0, stream>>>(obs_bf, w0t, nullptr, p, 128);

    // --- v MLP ---
    gemm_bt<1><<<dim3(32, 4), 256, 0, stream>>>(obs_bf, vw0t, v_b0, hva, 128);
    gemm_bt<1><<<dim3(32, 4), 256, 0, stream>>>(hva, vw1t, v_b1, hvb, 512);
    gemm_bt<1><<<dim3(32, 4), 256, 0, stream>>>(hvb, vw2t, v_b2, hva, 512);
    value_kernel<<<16, 256, 0, stream>>>(hva, v_w3, v_b3, out_value);

    // --- q MLP in 4 chunks ---
    for (int c = 0; c < 4; ++c) {
        int r0 = c * CHUNK;
        h0_kernel<<<CHUNK, 512, 0, stream>>>(p, category, q_w0, q_b0, ha, r0);
        gemm_bt<1><<<dim3(CHUNK / 128, 4), 256, 0, stream>>>(ha, w1t, q_b1, hb, 512);
        gemm_bt<1><<<dim3(CHUNK / 128, 4), 256, 0, stream>>>(hb, w2t, q_b2, ha, 512);
        adv_kernel<<<CHUNK * 16 / 256, 256, 0, stream>>>(ha, w3t, q_b3, out_adv, r0);
    }

    // --- nbias = zeros ---
    zero_kernel<<<512, 256, 0, stream>>>(out_nbias, B_SZ * S_N);
}

// Round 2
// 614.088 us; speedup vs baseline: 1.4688x; 1.4688x over previous
//
#include <hip/hip_runtime.h>
#include <hip/hip_bf16.h>

// Problem constants
#define B_SZ   4096
#define OBS_N  128
#define L_N    4
#define D_N    8
#define BINS_N 16
#define S_N    32          // L*D
#define HID    512
#define CHUNK  32768       // q-MLP rows per chunk (B*S/4)

// Row ordering for the q pipeline is S-MAJOR: global row r' = s*4096 + b.
// Chunk c covers s in [c*8, c*8+8), all 4096 b. This makes the layer-3
// diagonal (rows sharing s need the same 16 output cols) contiguous.

typedef __bf16 bf16x8_t __attribute__((ext_vector_type(8)));
typedef float  f32x4_t  __attribute__((ext_vector_type(4)));

__device__ inline float fast_tanh(float x) {
    float xc = fminf(fmaxf(x, -15.f), 15.f);
    float e  = __expf(2.f * xc);
    return (e - 1.f) * __builtin_amdgcn_rcpf(e + 1.f);
}

__device__ inline void gld_lds16(const void* g, void* l) {
    __builtin_amdgcn_global_load_lds(
        (const __attribute__((address_space(1))) void*)g,
        (__attribute__((address_space(3))) void*)l, 16, 0, 0);
}

// ---------------- prep kernels ----------------

// dst (N, Kd) bf16 = transpose of src (Ksrc, N) fp32 rows [k0src, k0src+Kcopy), zero-pad k>=Kcopy
__global__ __launch_bounds__(256) void transpose_cast(
    const float* __restrict__ src, __hip_bfloat16* __restrict__ dst,
    int N, int Kcopy, int Kd, int k0src)
{
    int idx = blockIdx.x * 256 + threadIdx.x;
    if (idx >= N * Kd) return;
    int n = idx / Kd, k = idx % Kd;
    float v = (k < Kcopy) ? src[(size_t)(k0src + k) * N + n] : 0.f;
    dst[idx] = __float2bfloat16(v);
}

__global__ __launch_bounds__(256) void cast_kernel(
    const float* __restrict__ src, __hip_bfloat16* __restrict__ dst, int n)
{
    int i = blockIdx.x * 256 + threadIdx.x;
    if (i < n) dst[i] = __float2bfloat16(src[i]);
}

__global__ __launch_bounds__(256) void zero_kernel(float* __restrict__ p, int n)
{
    int i = blockIdx.x * 256 + threadIdx.x;
    if (i < n) p[i] = 0.f;
}

// ---------------- GEMM (m97-style) ----------------
// C(M,512) = A(M,K) @ Bt(512,K)^T ; EPI=0: store fp32 raw; EPI=1: bf16(tanh(acc+bias))
template <int EPI>
__global__ __launch_bounds__(256) void gemm_bt(
    const __hip_bfloat16* __restrict__ A,
    const __hip_bfloat16* __restrict__ Bt,
    const float* __restrict__ bias,
    void* __restrict__ Cout,
    int K)
{
    __shared__ __hip_bfloat16 As[128 * 32];
    __shared__ __hip_bfloat16 Bs[128 * 32];
    const int tid  = threadIdx.x;
    const int wave = tid >> 6, lane = tid & 63;
    const int quad = lane >> 4, t = lane & 15;
    const int wr = wave >> 1, wc = wave & 1;
    const long m0 = (long)blockIdx.x * 128;
    const int  n0 = blockIdx.y * 128;

    f32x4_t acc[4][4] = {};

    const int lrow  = lane >> 2;       // 0..15
    const int lkoff = (lane & 3) * 8;  // element offset within 32-wide K chunk

    const __hip_bfloat16* Ag0 = A  + (m0 + wave * 32 +      lrow) * (long)K + lkoff;
    const __hip_bfloat16* Ag1 = A  + (m0 + wave * 32 + 16 + lrow) * (long)K + lkoff;
    const __hip_bfloat16* Bg0 = Bt + (long)(n0 + wave * 32 +      lrow) * K + lkoff;
    const __hip_bfloat16* Bg1 = Bt + (long)(n0 + wave * 32 + 16 + lrow) * K + lkoff;
    __hip_bfloat16* AsB0 = &As[(wave * 32) * 32];
    __hip_bfloat16* AsB1 = &As[(wave * 32 + 16) * 32];
    __hip_bfloat16* BsB0 = &Bs[(wave * 32) * 32];
    __hip_bfloat16* BsB1 = &Bs[(wave * 32 + 16) * 32];

    for (int k0 = 0; k0 < K; k0 += 32) {
        gld_lds16(Ag0 + k0, AsB0);
        gld_lds16(Ag1 + k0, AsB1);
        gld_lds16(Bg0 + k0, BsB0);
        gld_lds16(Bg1 + k0, BsB1);
        __syncthreads();
        bf16x8_t af[4], bfr[4];
        #pragma unroll
        for (int i = 0; i < 4; ++i)
            af[i] = *(const bf16x8_t*)&As[(wr * 64 + i * 16 + t) * 32 + quad * 8];
        #pragma unroll
        for (int j = 0; j < 4; ++j)
            bfr[j] = *(const bf16x8_t*)&Bs[(wc * 64 + j * 16 + t) * 32 + quad * 8];
        #pragma unroll
        for (int i = 0; i < 4; ++i)
            #pragma unroll
            for (int j = 0; j < 4; ++j)
                acc[i][j] = __builtin_amdgcn_mfma_f32_16x16x32_bf16(af[i], bfr[j], acc[i][j], 0, 0, 0);
        __syncthreads();
    }

    #pragma unroll
    for (int i = 0; i < 4; ++i) {
        const long rbase = m0 + wr * 64 + i * 16 + quad * 4;
        #pragma unroll
        for (int j = 0; j < 4; ++j) {
            const int col = n0 + wc * 64 + j * 16 + t;
            #pragma unroll
            for (int r = 0; r < 4; ++r) {
                float v = acc[i][j][r];
                if constexpr (EPI == 1) {
                    v = fast_tanh(v + bias[col]);
                    ((__hip_bfloat16*)Cout)[(rbase + r) * 512 + col] = __float2bfloat16(v);
                } else {
                    ((float*)Cout)[(rbase + r) * 512 + col] = v;
                }
            }
        }
    }
}

// ---------------- q layer 0: h0 = tanh(p[b] + actions(b,s)@W0b + b0) ----------------
// S-MAJOR: chunk-local row lr -> global row r = r0+lr, b = r & 4095, s = r >> 12.
__global__ __launch_bounds__(512) void h0_kernel(
    const float* __restrict__ p,         // (4096,512) fp32 = obs @ W0[:128]
    const int* __restrict__ category,    // (4096,4,8)
    const float* __restrict__ qw0,       // (136,512) fp32 (rows 128..135 = action part)
    const float* __restrict__ qb0,       // (512)
    __hip_bfloat16* __restrict__ h0,     // (CHUNK,512)
    int r0)
{
    int lr = blockIdx.x;
    int n  = threadIdx.x;
    int r  = r0 + lr;
    int b  = r & 4095, s = r >> 12;
    __shared__ float act[8];
    if (n < 8) {
        int d = n;
        int U = (s >> 3) + ((d < (s & 7)) ? 1 : 0);
        float a = 0.f;
        if (U > 0) {
            float w = 0.125f, cum = 0.f;
            for (int j = 0; j < U; ++j) {
                cum += (float)category[b * 32 + j * 8 + d] * w;
                if (j == U - 1) a = -1.f + cum + 0.5f * w;
                w *= 0.0625f;
            }
        }
        act[d] = a;
    }
    __syncthreads();
    float v = p[(size_t)b * 512 + n] + qb0[n];
    #pragma unroll
    for (int d = 0; d < 8; ++d)
        v = fmaf(act[d], qw0[(128 + d) * 512 + n], v);
    h0[(size_t)lr * 512 + n] = __float2bfloat16(fast_tanh(v));
}

// ---------------- q layer 3 (diagonal only), MFMA on s-major rows ----------------
// Per chunk: 8 s-values x 4096 b. Block = 128 rows (one s) x 16 out cols, K=512.
// Grid 256 blocks x 256 thr. Wave w handles rows [w*32, w*32+32). No LDS:
// A-frags and B-frags loaded straight to VGPRs (16B/lane, 64B row segments).
__global__ __launch_bounds__(256) void adv_kernel(
    const __hip_bfloat16* __restrict__ h2,   // (CHUNK,512) s-major
    const __hip_bfloat16* __restrict__ w3t,  // (512,512): [out][k]
    const float* __restrict__ qb3,
    float* __restrict__ advout,              // (4096,512) at d_out+4096
    int c)                                   // chunk index
{
    const int bid = blockIdx.x;
    const int sl = bid >> 5, mb = bid & 31;
    const int s  = c * 8 + sl;
    const int tid  = threadIdx.x;
    const int wave = tid >> 6, lane = tid & 63;
    const int quad = lane >> 4, t = lane & 15;

    const __hip_bfloat16* A = h2 + ((size_t)sl * 4096 + (size_t)mb * 128) * 512;
    const __hip_bfloat16* Ap0 = A + ((size_t)(wave * 32 + t)) * 512 + quad * 8;
    const __hip_bfloat16* Ap1 = Ap0 + 16 * 512;
    const __hip_bfloat16* Wp  = w3t + ((size_t)(s * 16 + t)) * 512 + quad * 8;

    f32x4_t acc0 = {}, acc1 = {};
    #pragma unroll
    for (int ks = 0; ks < 16; ++ks) {
        bf16x8_t bq = *(const bf16x8_t*)(Wp  + ks * 32);
        bf16x8_t a0 = *(const bf16x8_t*)(Ap0 + ks * 32);
        bf16x8_t a1 = *(const bf16x8_t*)(Ap1 + ks * 32);
        acc0 = __builtin_amdgcn_mfma_f32_16x16x32_bf16(a0, bq, acc0, 0, 0, 0);
        acc1 = __builtin_amdgcn_mfma_f32_16x16x32_bf16(a1, bq, acc1, 0, 0, 0);
    }

    const int ocol = s * 16 + t;
    const float bias = qb3[ocol];
    const int brow = mb * 128 + wave * 32 + quad * 4;
    #pragma unroll
    for (int r = 0; r < 4; ++r) {
        advout[(size_t)(brow + r) * 512 + ocol]      = acc0[r] + bias;
        advout[(size_t)(brow + 16 + r) * 512 + ocol] = acc1[r] + bias;
    }
}

// ---------------- v final layer ----------------
__device__ inline float blo(unsigned u) { return __uint_as_float(u << 16); }
__device__ inline float bhi(unsigned u) { return __uint_as_float(u & 0xffff0000u); }

__global__ __launch_bounds__(256) void value_kernel(
    const __hip_bfloat16* __restrict__ hv2,  // (4096,512)
    const float* __restrict__ vw3,           // (512,1)
    const float* __restrict__ vb3,
    float* __restrict__ out)
{
    int b = blockIdx.x * 256 + threadIdx.x;
    if (b >= 4096) return;
    const uint4* h = (const uint4*)(hv2 + (size_t)b * 512);
    float acc = 0.f;
    for (int i = 0; i < 64; ++i) {
        uint4 hu = h[i];
        const float* w = vw3 + i * 8;
        acc = fmaf(blo(hu.x), w[0], acc); acc = fmaf(bhi(hu.x), w[1], acc);
        acc = fmaf(blo(hu.y), w[2], acc); acc = fmaf(bhi(hu.y), w[3], acc);
        acc = fmaf(blo(hu.z), w[4], acc); acc = fmaf(bhi(hu.z), w[5], acc);
        acc = fmaf(blo(hu.w), w[6], acc); acc = fmaf(bhi(hu.w), w[7], acc);
    }
    out[b] = acc + vb3[0];
}

// ---------------- launch ----------------
extern "C" void kernel_launch(void* const* d_in, const int* in_sizes, int n_in,
                              void* d_out, int out_size, void* d_ws, size_t ws_size,
                              hipStream_t stream) {
    const float* obs      = (const float*)d_in[0];
    const int*   category = (const int*)d_in[1];
    const float* v_w0 = (const float*)d_in[2];
    const float* v_b0 = (const float*)d_in[3];
    const float* v_w1 = (const float*)d_in[4];
    const float* v_b1 = (const float*)d_in[5];
    const float* v_w2 = (const float*)d_in[6];
    const float* v_b2 = (const float*)d_in[7];
    const float* v_w3 = (const float*)d_in[8];
    const float* v_b3 = (const float*)d_in[9];
    const float* q_w0 = (const float*)d_in[10];
    const float* q_b0 = (const float*)d_in[11];
    const float* q_w1 = (const float*)d_in[12];
    const float* q_b1 = (const float*)d_in[13];
    const float* q_w2 = (const float*)d_in[14];
    const float* q_b2 = (const float*)d_in[15];
    const float* q_w3 = (const float*)d_in[16];
    const float* q_b3 = (const float*)d_in[17];

    char* ws = (char*)d_ws;
    __hip_bfloat16* obs_bf = (__hip_bfloat16*)(ws + 0);              // 1 MB
    __hip_bfloat16* w0t    = (__hip_bfloat16*)(ws + 1048576);        // (512,128)
    __hip_bfloat16* w1t    = (__hip_bfloat16*)(ws + 1179648);        // (512,512)
    __hip_bfloat16* w2t    = (__hip_bfloat16*)(ws + 1703936);
    __hip_bfloat16* w3t    = (__hip_bfloat16*)(ws + 2228224);
    __hip_bfloat16* vw0t   = (__hip_bfloat16*)(ws + 2752512);        // (512,128)
    __hip_bfloat16* vw1t   = (__hip_bfloat16*)(ws + 2883584);
    __hip_bfloat16* vw2t   = (__hip_bfloat16*)(ws + 3407872);
    float*          p      = (float*)         (ws + 3932160);        // (4096,512) fp32
    __hip_bfloat16* hva    = (__hip_bfloat16*)(ws + 12320768);       // (4096,512)
    __hip_bfloat16* hvb    = (__hip_bfloat16*)(ws + 16515072);
    __hip_bfloat16* ha     = (__hip_bfloat16*)(ws + 20709376);       // (CHUNK,512)
    __hip_bfloat16* hb     = (__hip_bfloat16*)(ws + 54263808);       // ends 87.8 MB

    float* out       = (float*)d_out;
    float* out_value = out;
    float* out_adv   = out + 4096;
    float* out_nbias = out + 4096 + (size_t)B_SZ * 512;

    // --- prep: casts + weight transposes ---
    cast_kernel<<<2048, 256, 0, stream>>>(obs, obs_bf, B_SZ * OBS_N);
    transpose_cast<<<256,  256, 0, stream>>>(q_w0, w0t,  512, 128, 128, 0);
    transpose_cast<<<1024, 256, 0, stream>>>(q_w1, w1t,  512, 512, 512, 0);
    transpose_cast<<<1024, 256, 0, stream>>>(q_w2, w2t,  512, 512, 512, 0);
    transpose_cast<<<1024, 256, 0, stream>>>(q_w3, w3t,  512, 512, 512, 0);
    transpose_cast<<<256,  256, 0, stream>>>(v_w0, vw0t, 512, 128, 128, 0);
    transpose_cast<<<1024, 256, 0, stream>>>(v_w1, vw1t, 512, 512, 512, 0);
    transpose_cast<<<1024, 256, 0, stream>>>(v_w2, vw2t, 512, 512, 512, 0);

    // --- p = obs @ W0[:128] (fp32 out, no activation) ---
    gemm_bt<0><<<dim3(32, 4), 256, 0, stream>>>(obs_bf, w0t, nullptr, p, 128);

    // --- v MLP ---
    gemm_bt<1><<<dim3(32, 4), 256, 0, stream>>>(obs_bf, vw0t, v_b0, hva, 128);
    gemm_bt<1><<<dim3(32, 4), 256, 0, stream>>>(hva, vw1t, v_b1, hvb, 512);
    gemm_bt<1><<<dim3(32, 4), 256, 0, stream>>>(hvb, vw2t, v_b2, hva, 512);
    value_kernel<<<16, 256, 0, stream>>>(hva, v_w3, v_b3, out_value);

    // --- q MLP in 4 chunks (s-major rows) ---
    for (int c = 0; c < 4; ++c) {
        int r0 = c * CHUNK;
        h0_kernel<<<CHUNK, 512, 0, stream>>>(p, category, q_w0, q_b0, ha, r0);
        gemm_bt<1><<<dim3(CHUNK / 128, 4), 256, 0, stream>>>(ha, w1t, q_b1, hb, 512);
        gemm_bt<1><<<dim3(CHUNK / 128, 4), 256, 0, stream>>>(hb, w2t, q_b2, ha, 512);
        adv_kernel<<<256, 256, 0, stream>>>(ha, w3t, q_b3, out_adv, c);
    }

    // --- nbias = zeros ---
    zero_kernel<<<512, 256, 0, stream>>>(out_nbias, B_SZ * S_N);
}

// Round 3
// 522.844 us; speedup vs baseline: 1.7252x; 1.1745x over previous
//
#include <hip/hip_runtime.h>
#include <hip/hip_bf16.h>

// Problem constants
#define B_SZ   4096
#define OBS_N  128
#define L_N    4
#define D_N    8
#define BINS_N 16
#define S_N    32          // L*D
#define HID    512
#define CHUNK  32768       // q-MLP rows per chunk (B*S/4)

// Row ordering for the q pipeline is S-MAJOR: global row r = s*4096 + b.
// Chunk c covers s in [c*8, c*8+8), all 4096 b. This makes the layer-3
// diagonal (rows sharing s need the same 16 output cols) contiguous.

typedef __bf16 bf16x8_t __attribute__((ext_vector_type(8)));
typedef float  f32x4_t  __attribute__((ext_vector_type(4)));

__device__ inline float fast_tanh(float x) {
    float xc = fminf(fmaxf(x, -15.f), 15.f);
    float e  = __expf(2.f * xc);
    return (e - 1.f) * __builtin_amdgcn_rcpf(e + 1.f);
}

__device__ inline void gld_lds16(const void* g, void* l) {
    __builtin_amdgcn_global_load_lds(
        (const __attribute__((address_space(1))) void*)g,
        (__attribute__((address_space(3))) void*)l, 16, 0, 0);
}

// ---------------- prep kernels ----------------

// dst (N, Kd) bf16 = transpose of src (Ksrc, N) fp32 rows [k0src, k0src+Kcopy), zero-pad k>=Kcopy
__global__ __launch_bounds__(256) void transpose_cast(
    const float* __restrict__ src, __hip_bfloat16* __restrict__ dst,
    int N, int Kcopy, int Kd, int k0src)
{
    int idx = blockIdx.x * 256 + threadIdx.x;
    if (idx >= N * Kd) return;
    int n = idx / Kd, k = idx % Kd;
    float v = (k < Kcopy) ? src[(size_t)(k0src + k) * N + n] : 0.f;
    dst[idx] = __float2bfloat16(v);
}

__global__ __launch_bounds__(256) void cast_kernel(
    const float* __restrict__ src, __hip_bfloat16* __restrict__ dst, int n)
{
    int i = blockIdx.x * 256 + threadIdx.x;
    if (i < n) dst[i] = __float2bfloat16(src[i]);
}

__global__ __launch_bounds__(256) void zero_kernel(float* __restrict__ p, int n)
{
    int i = blockIdx.x * 256 + threadIdx.x;
    if (i < n) p[i] = 0.f;
}

// actions table, s-major: acts[(s*4096+b)*8 + d]. 1,048,576 threads, coalesced.
__global__ __launch_bounds__(256) void actions_kernel(
    const int* __restrict__ category,   // (4096,4,8)
    float* __restrict__ acts)           // (131072,8)
{
    int tid = blockIdx.x * 256 + threadIdx.x;  // = r*8 + d
    int d = tid & 7;
    int r = tid >> 3;
    int b = r & 4095, s = r >> 12;
    int U = (s >> 3) + ((d < (s & 7)) ? 1 : 0);
    float a = 0.f;
    if (U > 0) {
        float w = 0.125f, cum = 0.f;
        for (int j = 0; j < U; ++j) {
            cum += (float)category[b * 32 + j * 8 + d] * w;
            if (j == U - 1) a = -1.f + cum + 0.5f * w;
            w *= 0.0625f;
        }
    }
    acts[tid] = a;
}

// ---------------- GEMM (m97-style) ----------------
// C(M,512) = A(M,K) @ Bt(512,K)^T ; EPI=0: store fp32 raw; EPI=1: bf16(tanh(acc+bias))
template <int EPI>
__global__ __launch_bounds__(256) void gemm_bt(
    const __hip_bfloat16* __restrict__ A,
    const __hip_bfloat16* __restrict__ Bt,
    const float* __restrict__ bias,
    void* __restrict__ Cout,
    int K)
{
    __shared__ __hip_bfloat16 As[128 * 32];
    __shared__ __hip_bfloat16 Bs[128 * 32];
    const int tid  = threadIdx.x;
    const int wave = tid >> 6, lane = tid & 63;
    const int quad = lane >> 4, t = lane & 15;
    const int wr = wave >> 1, wc = wave & 1;
    const long m0 = (long)blockIdx.x * 128;
    const int  n0 = blockIdx.y * 128;

    f32x4_t acc[4][4] = {};

    const int lrow  = lane >> 2;       // 0..15
    const int lkoff = (lane & 3) * 8;  // element offset within 32-wide K chunk

    const __hip_bfloat16* Ag0 = A  + (m0 + wave * 32 +      lrow) * (long)K + lkoff;
    const __hip_bfloat16* Ag1 = A  + (m0 + wave * 32 + 16 + lrow) * (long)K + lkoff;
    const __hip_bfloat16* Bg0 = Bt + (long)(n0 + wave * 32 +      lrow) * K + lkoff;
    const __hip_bfloat16* Bg1 = Bt + (long)(n0 + wave * 32 + 16 + lrow) * K + lkoff;
    __hip_bfloat16* AsB0 = &As[(wave * 32) * 32];
    __hip_bfloat16* AsB1 = &As[(wave * 32 + 16) * 32];
    __hip_bfloat16* BsB0 = &Bs[(wave * 32) * 32];
    __hip_bfloat16* BsB1 = &Bs[(wave * 32 + 16) * 32];

    for (int k0 = 0; k0 < K; k0 += 32) {
        gld_lds16(Ag0 + k0, AsB0);
        gld_lds16(Ag1 + k0, AsB1);
        gld_lds16(Bg0 + k0, BsB0);
        gld_lds16(Bg1 + k0, BsB1);
        __syncthreads();
        bf16x8_t af[4], bfr[4];
        #pragma unroll
        for (int i = 0; i < 4; ++i)
            af[i] = *(const bf16x8_t*)&As[(wr * 64 + i * 16 + t) * 32 + quad * 8];
        #pragma unroll
        for (int j = 0; j < 4; ++j)
            bfr[j] = *(const bf16x8_t*)&Bs[(wc * 64 + j * 16 + t) * 32 + quad * 8];
        #pragma unroll
        for (int i = 0; i < 4; ++i)
            #pragma unroll
            for (int j = 0; j < 4; ++j)
                acc[i][j] = __builtin_amdgcn_mfma_f32_16x16x32_bf16(af[i], bfr[j], acc[i][j], 0, 0, 0);
        __syncthreads();
    }

    #pragma unroll
    for (int i = 0; i < 4; ++i) {
        const long rbase = m0 + wr * 64 + i * 16 + quad * 4;
        #pragma unroll
        for (int j = 0; j < 4; ++j) {
            const int col = n0 + wc * 64 + j * 16 + t;
            #pragma unroll
            for (int r = 0; r < 4; ++r) {
                float v = acc[i][j][r];
                if constexpr (EPI == 1) {
                    v = fast_tanh(v + bias[col]);
                    ((__hip_bfloat16*)Cout)[(rbase + r) * 512 + col] = __float2bfloat16(v);
                } else {
                    ((float*)Cout)[(rbase + r) * 512 + col] = v;
                }
            }
        }
    }
}

// ---------------- q layer 0: h0 = tanh(p[b] + acts(r)@W0b + b0) ----------------
// One WAVE per row; lane owns cols [lane*8, lane*8+8). 16 rows per wave,
// 64 rows per 256-thread block. Action weights (8x8 per lane) held in VGPRs.
__global__ __launch_bounds__(256) void h0_kernel(
    const float* __restrict__ p,         // (4096,512) fp32 = obs @ W0[:128]
    const float* __restrict__ acts,      // (131072,8) fp32 s-major
    const float* __restrict__ qw0,       // (136,512) fp32 (rows 128..135 = action part)
    const float* __restrict__ qb0,       // (512)
    __hip_bfloat16* __restrict__ h0,     // (CHUNK,512)
    int r0)
{
    const int wave = threadIdx.x >> 6, lane = threadIdx.x & 63;
    const int col0 = lane * 8;

    float w[8][8], bb[8];
    #pragma unroll
    for (int d = 0; d < 8; ++d) {
        float4 u0 = *(const float4*)&qw0[(128 + d) * 512 + col0];
        float4 u1 = *(const float4*)&qw0[(128 + d) * 512 + col0 + 4];
        w[d][0] = u0.x; w[d][1] = u0.y; w[d][2] = u0.z; w[d][3] = u0.w;
        w[d][4] = u1.x; w[d][5] = u1.y; w[d][6] = u1.z; w[d][7] = u1.w;
    }
    {
        float4 b0 = *(const float4*)&qb0[col0];
        float4 b1 = *(const float4*)&qb0[col0 + 4];
        bb[0] = b0.x; bb[1] = b0.y; bb[2] = b0.z; bb[3] = b0.w;
        bb[4] = b1.x; bb[5] = b1.y; bb[6] = b1.z; bb[7] = b1.w;
    }

    #pragma unroll 2
    for (int rr = 0; rr < 16; ++rr) {
        const int lr = blockIdx.x * 64 + wave * 16 + rr;
        const int b  = lr & 4095;
        const float4* pp = (const float4*)&p[(size_t)b * 512 + col0];
        float4 p0 = pp[0], p1 = pp[1];
        const float4* ap = (const float4*)&acts[(size_t)(r0 + lr) * 8];
        float4 a0 = ap[0], a1 = ap[1];
        float a[8] = {a0.x, a0.y, a0.z, a0.w, a1.x, a1.y, a1.z, a1.w};
        float v[8] = {p0.x + bb[0], p0.y + bb[1], p0.z + bb[2], p0.w + bb[3],
                      p1.x + bb[4], p1.y + bb[5], p1.z + bb[6], p1.w + bb[7]};
        #pragma unroll
        for (int d = 0; d < 8; ++d)
            #pragma unroll
            for (int cc = 0; cc < 8; ++cc)
                v[cc] = fmaf(a[d], w[d][cc], v[cc]);
        union { bf16x8_t vec; __hip_bfloat16 e[8]; } o;
        #pragma unroll
        for (int cc = 0; cc < 8; ++cc)
            o.e[cc] = __float2bfloat16(fast_tanh(v[cc]));
        *(bf16x8_t*)&h0[(size_t)lr * 512 + col0] = o.vec;
    }
}

// ---------------- q layer 3 (diagonal only), MFMA on s-major rows ----------------
__global__ __launch_bounds__(256) void adv_kernel(
    const __hip_bfloat16* __restrict__ h2,   // (CHUNK,512) s-major
    const __hip_bfloat16* __restrict__ w3t,  // (512,512): [out][k]
    const float* __restrict__ qb3,
    float* __restrict__ advout,              // (4096,512) at d_out+4096
    int c)                                   // chunk index
{
    const int bid = blockIdx.x;
    const int sl = bid >> 5, mb = bid & 31;
    const int s  = c * 8 + sl;
    const int tid  = threadIdx.x;
    const int wave = tid >> 6, lane = tid & 63;
    const int quad = lane >> 4, t = lane & 15;

    const __hip_bfloat16* A = h2 + ((size_t)sl * 4096 + (size_t)mb * 128) * 512;
    const __hip_bfloat16* Ap0 = A + ((size_t)(wave * 32 + t)) * 512 + quad * 8;
    const __hip_bfloat16* Ap1 = Ap0 + 16 * 512;
    const __hip_bfloat16* Wp  = w3t + ((size_t)(s * 16 + t)) * 512 + quad * 8;

    f32x4_t acc0 = {}, acc1 = {};
    #pragma unroll
    for (int ks = 0; ks < 16; ++ks) {
        bf16x8_t bq = *(const bf16x8_t*)(Wp  + ks * 32);
        bf16x8_t a0 = *(const bf16x8_t*)(Ap0 + ks * 32);
        bf16x8_t a1 = *(const bf16x8_t*)(Ap1 + ks * 32);
        acc0 = __builtin_amdgcn_mfma_f32_16x16x32_bf16(a0, bq, acc0, 0, 0, 0);
        acc1 = __builtin_amdgcn_mfma_f32_16x16x32_bf16(a1, bq, acc1, 0, 0, 0);
    }

    const int ocol = s * 16 + t;
    const float bias = qb3[ocol];
    const int brow = mb * 128 + wave * 32 + quad * 4;
    #pragma unroll
    for (int r = 0; r < 4; ++r) {
        advout[(size_t)(brow + r) * 512 + ocol]      = acc0[r] + bias;
        advout[(size_t)(brow + 16 + r) * 512 + ocol] = acc1[r] + bias;
    }
}

// ---------------- v final layer ----------------
__device__ inline float blo(unsigned u) { return __uint_as_float(u << 16); }
__device__ inline float bhi(unsigned u) { return __uint_as_float(u & 0xffff0000u); }

__global__ __launch_bounds__(256) void value_kernel(
    const __hip_bfloat16* __restrict__ hv2,  // (4096,512)
    const float* __restrict__ vw3,           // (512,1)
    const float* __restrict__ vb3,
    float* __restrict__ out)
{
    int b = blockIdx.x * 256 + threadIdx.x;
    if (b >= 4096) return;
    const uint4* h = (const uint4*)(hv2 + (size_t)b * 512);
    float acc = 0.f;
    for (int i = 0; i < 64; ++i) {
        uint4 hu = h[i];
        const float* w = vw3 + i * 8;
        acc = fmaf(blo(hu.x), w[0], acc); acc = fmaf(bhi(hu.x), w[1], acc);
        acc = fmaf(blo(hu.y), w[2], acc); acc = fmaf(bhi(hu.y), w[3], acc);
        acc = fmaf(blo(hu.z), w[4], acc); acc = fmaf(bhi(hu.z), w[5], acc);
        acc = fmaf(blo(hu.w), w[6], acc); acc = fmaf(bhi(hu.w), w[7], acc);
    }
    out[b] = acc + vb3[0];
}

// ---------------- launch ----------------
extern "C" void kernel_launch(void* const* d_in, const int* in_sizes, int n_in,
                              void* d_out, int out_size, void* d_ws, size_t ws_size,
                              hipStream_t stream) {
    const float* obs      = (const float*)d_in[0];
    const int*   category = (const int*)d_in[1];
    const float* v_w0 = (const float*)d_in[2];
    const float* v_b0 = (const float*)d_in[3];
    const float* v_w1 = (const float*)d_in[4];
    const float* v_b1 = (const float*)d_in[5];
    const float* v_w2 = (const float*)d_in[6];
    const float* v_b2 = (const float*)d_in[7];
    const float* v_w3 = (const float*)d_in[8];
    const float* v_b3 = (const float*)d_in[9];
    const float* q_w0 = (const float*)d_in[10];
    const float* q_b0 = (const float*)d_in[11];
    const float* q_w1 = (const float*)d_in[12];
    const float* q_b1 = (const float*)d_in[13];
    const float* q_w2 = (const float*)d_in[14];
    const float* q_b2 = (const float*)d_in[15];
    const float* q_w3 = (const float*)d_in[16];
    const float* q_b3 = (const float*)d_in[17];

    char* ws = (char*)d_ws;
    __hip_bfloat16* obs_bf = (__hip_bfloat16*)(ws + 0);              // 1 MB
    __hip_bfloat16* w0t    = (__hip_bfloat16*)(ws + 1048576);        // (512,128)
    __hip_bfloat16* w1t    = (__hip_bfloat16*)(ws + 1179648);        // (512,512)
    __hip_bfloat16* w2t    = (__hip_bfloat16*)(ws + 1703936);
    __hip_bfloat16* w3t    = (__hip_bfloat16*)(ws + 2228224);
    __hip_bfloat16* vw0t   = (__hip_bfloat16*)(ws + 2752512);        // (512,128)
    __hip_bfloat16* vw1t   = (__hip_bfloat16*)(ws + 2883584);
    __hip_bfloat16* vw2t   = (__hip_bfloat16*)(ws + 3407872);
    float*          p      = (float*)         (ws + 3932160);        // (4096,512) fp32
    __hip_bfloat16* hva    = (__hip_bfloat16*)(ws + 12320768);       // (4096,512)
    __hip_bfloat16* hvb    = (__hip_bfloat16*)(ws + 16515072);
    __hip_bfloat16* ha     = (__hip_bfloat16*)(ws + 20709376);       // (CHUNK,512)
    __hip_bfloat16* hb     = (__hip_bfloat16*)(ws + 54263808);       // +33.5 MB
    float*          acts   = (float*)         (ws + 87818240);       // (131072,8) fp32, ends ~92 MB

    float* out       = (float*)d_out;
    float* out_value = out;
    float* out_adv   = out + 4096;
    float* out_nbias = out + 4096 + (size_t)B_SZ * 512;

    // --- prep: casts + weight transposes + actions table ---
    cast_kernel<<<2048, 256, 0, stream>>>(obs, obs_bf, B_SZ * OBS_N);
    actions_kernel<<<4096, 256, 0, stream>>>(category, acts);
    transpose_cast<<<256,  256, 0, stream>>>(q_w0, w0t,  512, 128, 128, 0);
    transpose_cast<<<1024, 256, 0, stream>>>(q_w1, w1t,  512, 512, 512, 0);
    transpose_cast<<<1024, 256, 0, stream>>>(q_w2, w2t,  512, 512, 512, 0);
    transpose_cast<<<1024, 256, 0, stream>>>(q_w3, w3t,  512, 512, 512, 0);
    transpose_cast<<<256,  256, 0, stream>>>(v_w0, vw0t, 512, 128, 128, 0);
    transpose_cast<<<1024, 256, 0, stream>>>(v_w1, vw1t, 512, 512, 512, 0);
    transpose_cast<<<1024, 256, 0, stream>>>(v_w2, vw2t, 512, 512, 512, 0);

    // --- p = obs @ W0[:128] (fp32 out, no activation) ---
    gemm_bt<0><<<dim3(32, 4), 256, 0, stream>>>(obs_bf, w0t, nullptr, p, 128);

    // --- v MLP ---
    gemm_bt<1><<<dim3(32, 4), 256, 0, stream>>>(obs_bf, vw0t, v_b0, hva, 128);
    gemm_bt<1><<<dim3(32, 4), 256, 0, stream>>>(hva, vw1t, v_b1, hvb, 512);
    gemm_bt<1><<<dim3(32, 4), 256, 0, stream>>>(hvb, vw2t, v_b2, hva, 512);
    value_kernel<<<16, 256, 0, stream>>>(hva, v_w3, v_b3, out_value);

    // --- q MLP in 4 chunks (s-major rows) ---
    for (int c = 0; c < 4; ++c) {
        int r0 = c * CHUNK;
        h0_kernel<<<512, 256, 0, stream>>>(p, acts, q_w0, q_b0, ha, r0);
        gemm_bt<1><<<dim3(CHUNK / 128, 4), 256, 0, stream>>>(ha, w1t, q_b1, hb, 512);
        gemm_bt<1><<<dim3(CHUNK / 128, 4), 256, 0, stream>>>(hb, w2t, q_b2, ha, 512);
        adv_kernel<<<256, 256, 0, stream>>>(ha, w3t, q_b3, out_adv, c);
    }

    // --- nbias = zeros ---
    zero_kernel<<<512, 256, 0, stream>>>(out_nbias, B_SZ * S_N);
}